// Round 1
// baseline (103.239 us; speedup 1.0000x reference)
//
#include <hip/hip_runtime.h>

#define BATCH    8192
#define NF       39      // num_fields
#define ED       64      // embed dim
#define RANK     32
#define KST      40      // lane stride 80 B = 20 banks: lanes 0..7 -> bank-quads 0,20,8,28,16,4,24,12 (conflict-free b128)
#define NFRAG    15      // 5 l-slices x 3 k-chunks

typedef _Float16 half8  __attribute__((ext_vector_type(8)));
typedef float    f32x16 __attribute__((ext_vector_type(16)));

// One wave = one sample. W frags built IN-KERNEL into LDS (no prep kernel, no
// workspace -> no 256 MiB workspace re-poison fill in the timed region).
// x row via scalar s_load (uniform) -> embed gathers issue off SGPR bases.
// LDS = 15360 (Ws) + 20480 (Ef) = 35840 B -> 4 blocks/CU (was 3 at 52 KB).
__global__ __launch_bounds__(256, 4) void tfm_kernel(
    const int*   __restrict__ x,        // (B, NF)
    const float* __restrict__ embed,    // (100000, ED)
    const float* __restrict__ linw,     // (100000, 1)
    const float* __restrict__ lbias,    // (1,)
    const float* __restrict__ W0,       // (2, 32, NF)
    const float* __restrict__ W1,       // (3, 32, NF)
    float*       __restrict__ out)      // (B,)
{
    __shared__ __align__(16) _Float16 Ws[NFRAG * 64 * 8];   // 15360 B, A-frag layout
    __shared__ __align__(16) _Float16 Ef[4][ED][KST];       // 20480 B, wave-private [i][k]

    const int t    = threadIdx.x;
    const int lane = t & 63;
    const int w    = t >> 6;
    const int s    = __builtin_amdgcn_readfirstlane(blockIdx.x * 4 + w);

    // ---- uniform x row -> SGPRs (s_load; no vector round-trip, no readlanes) ----
    const int* __restrict__ xrow = x + s * NF;
    int xi[NF];
#pragma unroll
    for (int k = 0; k < NF; ++k) xi[k] = xrow[k];

    // ---- independent vector chain: linear term gather ----
    const int   xi_v = (lane < NF) ? x[s * NF + lane] : 0;
    const float lv   = (lane < NF) ? linw[xi_v] : 0.0f;
    const float bias = lbias[0];

    // ---- in-kernel W A-frag build (L2-hot 25 KB; overlaps the x s_load latency) ----
    // Ws[(l*3+kc)*64 + dl] = half8 of W row j=dl&31, k = kc*16 + (dl>>5)*8 + e
#pragma unroll
    for (int pass = 0; pass < 4; ++pass) {
        int d = pass * 256 + t;
        if (pass < 3 || d < NFRAG * 64) {
            int fid = d >> 6, dl = d & 63;
            int l = fid / 3, kc = fid % 3;
            int j = dl & 31, kh2 = dl >> 5;
            const float* base = (l < 2) ? (W0 + (l * RANK + j) * NF)
                                        : (W1 + ((l - 2) * RANK + j) * NF);
            half8 h;
#pragma unroll
            for (int e = 0; e < 8; ++e) {
                int k = kc * 16 + kh2 * 8 + e;
                h[e] = (k < NF) ? (_Float16)base[k] : (_Float16)0.0f;
            }
            *(half8*)&Ws[d * 8] = h;
        }
    }

    // ---- 39 coalesced 256 B row gathers, SGPR base + lane*4 ----
    float r[NF];
#pragma unroll
    for (int k = 0; k < NF; ++k)
        r[k] = embed[(size_t)xi[k] * ED + lane];

    // ---- pack f16 [i][k]; use order == load order -> graduated vmcnt waits ----
#pragma unroll
    for (int c5 = 0; c5 < 5; ++c5) {
        half8 hh;
#pragma unroll
        for (int e = 0; e < 8; ++e) {
            int k = c5 * 8 + e;
            hh[e] = (k < NF) ? (_Float16)r[k] : (_Float16)0.0f;
        }
        *(half8*)&Ef[w][lane][c5 * 8] = hh;   // 80 B lane stride: conflict-free
    }

    __syncthreads();   // Ws visible to all waves (Ef is wave-private)

    const half8* Wf = (const half8*)Ws;
    const int j  = lane & 31;
    const int kh = lane >> 5;
    float ssum = lv;

    half8 hz;
#pragma unroll
    for (int e = 0; e < 8; ++e) hz[e] = (_Float16)0.0f;

#pragma unroll
    for (int tile = 0; tile < 2; ++tile) {
        const int c = tile * 32 + j;
        half8 bf[3];
        bf[0] = *(const half8*)&Ef[w][c][kh * 8];
        bf[1] = *(const half8*)&Ef[w][c][16 + kh * 8];
        {
            // kc=2 covers k=32..47: kh=0 slice is Ef[c][32..39]; kh=1 slice is
            // k=40..47 which is zero on the A side too -> feed explicit zeros
            // (cannot blind-read: beyond-row LDS may hold NaN bit patterns, 0*NaN=NaN)
            half8 b2 = *(const half8*)&Ef[w][c][32];
            bf[2] = kh ? hz : b2;
        }

        // phase W0: 2 accumulators, folded immediately (tree reduce: no fast-math,
        // a serial ssum+= chain would be 16 dependent FMAs)
        {
            f32x16 a0, a1;
#pragma unroll
            for (int e = 0; e < 16; ++e) { a0[e] = 0.0f; a1[e] = 0.0f; }
#pragma unroll
            for (int kc = 0; kc < 3; ++kc) {
                a0 = __builtin_amdgcn_mfma_f32_32x32x16_f16(Wf[(0 * 3 + kc) * 64 + lane], bf[kc], a0, 0, 0, 0);
                a1 = __builtin_amdgcn_mfma_f32_32x32x16_f16(Wf[(1 * 3 + kc) * 64 + lane], bf[kc], a1, 0, 0, 0);
            }
            float p0 = 0.f, p1 = 0.f, p2 = 0.f, p3 = 0.f;
#pragma unroll
            for (int e = 0; e < 4; ++e) {
                p0 += a0[e]      * a1[e];
                p1 += a0[4 + e]  * a1[4 + e];
                p2 += a0[8 + e]  * a1[8 + e];
                p3 += a0[12 + e] * a1[12 + e];
            }
            ssum += (p0 + p1) + (p2 + p3);
        }
        // phase W1: 3 accumulators (reuses W0's registers)
        {
            f32x16 c0, c1, c2;
#pragma unroll
            for (int e = 0; e < 16; ++e) { c0[e] = 0.0f; c1[e] = 0.0f; c2[e] = 0.0f; }
#pragma unroll
            for (int kc = 0; kc < 3; ++kc) {
                c0 = __builtin_amdgcn_mfma_f32_32x32x16_f16(Wf[(2 * 3 + kc) * 64 + lane], bf[kc], c0, 0, 0, 0);
                c1 = __builtin_amdgcn_mfma_f32_32x32x16_f16(Wf[(3 * 3 + kc) * 64 + lane], bf[kc], c1, 0, 0, 0);
                c2 = __builtin_amdgcn_mfma_f32_32x32x16_f16(Wf[(4 * 3 + kc) * 64 + lane], bf[kc], c2, 0, 0, 0);
            }
            float q0 = 0.f, q1 = 0.f, q2 = 0.f, q3 = 0.f;
#pragma unroll
            for (int e = 0; e < 4; ++e) {
                q0 += c0[e]      * c1[e]      * c2[e];
                q1 += c0[4 + e]  * c1[4 + e]  * c2[4 + e];
                q2 += c0[8 + e]  * c1[8 + e]  * c2[8 + e];
                q3 += c0[12 + e] * c1[12 + e] * c2[12 + e];
            }
            ssum += (q0 + q1) + (q2 + q3);
        }
    }

    // ---- 64-lane reduce, lane 0 writes ----
#pragma unroll
    for (int off = 32; off > 0; off >>= 1) ssum += __shfl_down(ssum, off, 64);
    if (lane == 0) out[s] = ssum + bias;
}

extern "C" void kernel_launch(void* const* d_in, const int* in_sizes, int n_in,
                              void* d_out, int out_size, void* d_ws, size_t ws_size,
                              hipStream_t stream) {
    const int*   x     = (const int*)  d_in[0];
    const float* embed = (const float*)d_in[1];
    const float* linw  = (const float*)d_in[2];
    const float* lbias = (const float*)d_in[3];
    const float* W0    = (const float*)d_in[4];
    const float* W1    = (const float*)d_in[5];
    float*       out   = (float*)d_out;
    // d_ws intentionally unused: no prep kernel, no workspace -> no poison fill.

    // 2048 blocks x 4 waves x 1 sample = 8192
    tfm_kernel<<<BATCH / 4, 256, 0, stream>>>(x, embed, linw, lbias, W0, W1, out);
}

// Round 2
// 93.297 us; speedup vs baseline: 1.1066x; 1.1066x over previous
//
#include <hip/hip_runtime.h>

#define BATCH    8192
#define NF       39      // num_fields
#define ED       64      // embed dim
#define RANK     32
#define NFRAG    15      // 5 l-slices x 3 k-chunks

typedef _Float16 half8  __attribute__((ext_vector_type(8)));
typedef float    f32x16 __attribute__((ext_vector_type(16)));

// ---- prep: build the 15 W A-fragments in per-lane MFMA layout (proven path) ----
// wsW[(l*3+kc)*64 + lane] = half8 of W row j=lane&31, k = kc*16 + (lane>>5)*8 + e.
__global__ void prep_w(const float* __restrict__ W0,
                       const float* __restrict__ W1,
                       half8* __restrict__ wsW) {
    int d = blockIdx.x * 256 + threadIdx.x;
    if (d >= NFRAG * 64) return;
    int fid  = d >> 6;
    int lane = d & 63;
    int l = fid / 3, kc = fid % 3;
    int j = lane & 31, kh = lane >> 5;
    const float* base = (l < 2) ? (W0 + (l * RANK + j) * NF)
                                : (W1 + ((l - 2) * RANK + j) * NF);
    half8 h;
#pragma unroll
    for (int e = 0; e < 8; ++e) {
        int k = kc * 16 + kh * 8 + e;
        h[e] = (k < NF) ? (_Float16)base[k] : (_Float16)0.0f;
    }
    wsW[d] = h;
}

union H8U { half8 h; unsigned int u[4]; };

// One wave = one sample. A-frags from LDS (block-staged once, coalesced).
// B-frags built IN REGISTERS from the gather results via v_permlane32_swap:
// lane i holds embed column i for all k; tile0 needs col=lane&31, tile1 col=
// (lane&31)+32 -> a pure lane[i]<->lane[i+32] exchange. One swap yields BOTH
// tiles' fragment words (a'={a.lo,b.lo}, b'={a.hi,b.hi}). Deletes the 36 KB
// Ef buffer + 11 LDS ops/wave + the pack->sync->read serialization.
__global__ __launch_bounds__(256, 4) void tfm_kernel(
    const int*   __restrict__ x,        // (B, NF)
    const float* __restrict__ embed,    // (100000, ED)
    const float* __restrict__ linw,     // (100000, 1)
    const float* __restrict__ lbias,    // (1,)
    const half8* __restrict__ wsW,      // [NFRAG][64]
    float*       __restrict__ out)      // (B,)
{
    __shared__ __align__(16) _Float16 Ws[NFRAG * 64 * 8];   // 15360 B total LDS

    const int t    = threadIdx.x;
    const int lane = t & 63;
    const int w    = t >> 6;
    const int s    = blockIdx.x * 4 + w;     // one sample per wave

    // ---- issue the gather chain first (proven: vector x load + readlane) ----
    const int xi_v = (lane < NF) ? x[s * NF + lane] : 0;
    const float lv = (lane < NF) ? linw[xi_v] : 0.0f;

    float r[NF];
#pragma unroll
    for (int k = 0; k < NF; ++k) {
        int xi = __builtin_amdgcn_readlane(xi_v, k);   // uniform -> SGPR base
        r[k] = embed[(size_t)xi * ED + lane];          // coalesced 256B row
    }

    // ---- stage W frags into LDS (independent coalesced loads, overlap gather) ----
    {
        const uint4* src = (const uint4*)wsW;
        uint4*       dst = (uint4*)Ws;
#pragma unroll
        for (int i = 0; i < 3; ++i)                    // 960 frag-words / 256 thr
            dst[i * 256 + t] = src[i * 256 + t];
        if (t < NFRAG * 64 - 768) dst[768 + t] = src[768 + t];
    }

    const float bias = lbias[0];

    // ---- B-frags in registers: pack f16 (RNE) then permlane32_swap ----
    // pkA = k slice kc*16..+7 (kh=0), pkB = kc*16+8..+15 (kh=1). After swap:
    //   A' lane l = l<32 ? own pkA (col l, kh=0)     : partner pkB (col l-32, kh=1)  == bf_tile0
    //   B' lane l = l<32 ? partner pkA (col l+32)    : own pkB (col l)               == bf_tile1
    // kc=2 tail (k=39..47) gets explicit zeros (A-side Ws is zero there too).
    half8 bf0[3], bf1[3];
#pragma unroll
    for (int kc = 0; kc < 3; ++kc) {
        H8U A, B;
#pragma unroll
        for (int e = 0; e < 8; ++e) {
            int kA = kc * 16 + e;
            int kB = kc * 16 + 8 + e;
            A.h[e] = (kA < NF) ? (_Float16)r[kA] : (_Float16)0.0f;
            B.h[e] = (kB < NF) ? (_Float16)r[kB] : (_Float16)0.0f;
        }
#pragma unroll
        for (int q = 0; q < 4; ++q)
            asm volatile("v_permlane32_swap_b32 %0, %1"
                         : "+v"(A.u[q]), "+v"(B.u[q]));
        bf0[kc] = A.h;
        bf1[kc] = B.h;
    }

    __syncthreads();   // Ws visible to all waves

    const half8* Wf = (const half8*)Ws;
    float ssum = lv;

    // Per tile: phase W0 (2 acc, fold product), phase W1 (3 acc, fold triple).
    // Tree folds: no fast-math, serial ssum+= would be a 16-deep dependent chain.
#define TILE_BODY(BF)                                                          \
    {                                                                          \
        f32x16 a0, a1;                                                         \
        _Pragma("unroll")                                                      \
        for (int e = 0; e < 16; ++e) { a0[e] = 0.0f; a1[e] = 0.0f; }           \
        _Pragma("unroll")                                                      \
        for (int kc = 0; kc < 3; ++kc) {                                       \
            a0 = __builtin_amdgcn_mfma_f32_32x32x16_f16(                       \
                     Wf[(0 * 3 + kc) * 64 + lane], BF[kc], a0, 0, 0, 0);       \
            a1 = __builtin_amdgcn_mfma_f32_32x32x16_f16(                       \
                     Wf[(1 * 3 + kc) * 64 + lane], BF[kc], a1, 0, 0, 0);       \
        }                                                                      \
        float p0 = 0.f, p1 = 0.f, p2 = 0.f, p3 = 0.f;                          \
        _Pragma("unroll")                                                      \
        for (int e = 0; e < 4; ++e) {                                          \
            p0 += a0[e]      * a1[e];                                          \
            p1 += a0[4 + e]  * a1[4 + e];                                      \
            p2 += a0[8 + e]  * a1[8 + e];                                      \
            p3 += a0[12 + e] * a1[12 + e];                                     \
        }                                                                      \
        ssum += (p0 + p1) + (p2 + p3);                                         \
        f32x16 c0, c1, c2;                                                     \
        _Pragma("unroll")                                                      \
        for (int e = 0; e < 16; ++e) { c0[e] = 0.0f; c1[e] = 0.0f; c2[e] = 0.0f; } \
        _Pragma("unroll")                                                      \
        for (int kc = 0; kc < 3; ++kc) {                                       \
            c0 = __builtin_amdgcn_mfma_f32_32x32x16_f16(                       \
                     Wf[(2 * 3 + kc) * 64 + lane], BF[kc], c0, 0, 0, 0);       \
            c1 = __builtin_amdgcn_mfma_f32_32x32x16_f16(                       \
                     Wf[(3 * 3 + kc) * 64 + lane], BF[kc], c1, 0, 0, 0);       \
            c2 = __builtin_amdgcn_mfma_f32_32x32x16_f16(                       \
                     Wf[(4 * 3 + kc) * 64 + lane], BF[kc], c2, 0, 0, 0);       \
        }                                                                      \
        float q0 = 0.f, q1 = 0.f, q2 = 0.f, q3 = 0.f;                          \
        _Pragma("unroll")                                                      \
        for (int e = 0; e < 4; ++e) {                                          \
            q0 += c0[e]      * c1[e]      * c2[e];                             \
            q1 += c0[4 + e]  * c1[4 + e]  * c2[4 + e];                         \
            q2 += c0[8 + e]  * c1[8 + e]  * c2[8 + e];                         \
            q3 += c0[12 + e] * c1[12 + e] * c2[12 + e];                        \
        }                                                                      \
        ssum += (q0 + q1) + (q2 + q3);                                         \
    }

    TILE_BODY(bf0)   // columns 0..31
    TILE_BODY(bf1)   // columns 32..63
#undef TILE_BODY

    // ---- 64-lane reduce, lane 0 writes ----
#pragma unroll
    for (int off = 32; off > 0; off >>= 1) ssum += __shfl_down(ssum, off, 64);
    if (lane == 0) out[s] = ssum + bias;
}

extern "C" void kernel_launch(void* const* d_in, const int* in_sizes, int n_in,
                              void* d_out, int out_size, void* d_ws, size_t ws_size,
                              hipStream_t stream) {
    const int*   x     = (const int*)  d_in[0];
    const float* embed = (const float*)d_in[1];
    const float* linw  = (const float*)d_in[2];
    const float* lbias = (const float*)d_in[3];
    const float* W0    = (const float*)d_in[4];
    const float* W1    = (const float*)d_in[5];
    float*       out   = (float*)d_out;
    half8*       wsW   = (half8*)d_ws;          // 15*64*16 B = 15360 B

    prep_w<<<(NFRAG * 64 + 255) / 256, 256, 0, stream>>>(W0, W1, wsW);
    // 2048 blocks x 4 waves x 1 sample = 8192
    tfm_kernel<<<BATCH / 4, 256, 0, stream>>>(x, embed, linw, lbias, wsW, out);
}